// Round 18
// baseline (267.456 us; speedup 1.0000x reference)
//
#include <hip/hip_runtime.h>

#define N_NODES 100000
#define IN_C 32
#define HID_C 64
#define OUT_C 5
#define N_EDGES 1600000
#define SCAN_BLK 1024
#define N_SCAN_BLKS ((N_NODES + SCAN_BLK - 1) / SCAN_BLK)   // 98
#define N_TILES ((N_NODES + 63) / 64)                        // 1563
#define N_REP 8

// dst-space partitioning for XCD-local scatter writes — used ONLY in fill.
#define N_PART 8
#define PART_NODES 12500
#define PART_BLOCKS 2048

__device__ __forceinline__ unsigned short f2bf(float f) {
  unsigned int u = __float_as_uint(f);
  unsigned int r = (u + 0x7FFFu + ((u >> 16) & 1u)) >> 16;  // RNE
  return (unsigned short)r;
}
__device__ __forceinline__ float bf2f(unsigned short b) {
  return __uint_as_float(((unsigned int)b) << 16);
}

// ---------------------------------------------------------------------------
// Convert x (f32 [N,32]) -> xb (bf16).
// ---------------------------------------------------------------------------
__global__ __launch_bounds__(256) void convert_x_kernel(
    const float* __restrict__ x, unsigned short* __restrict__ xb) {
  int t = blockIdx.x * blockDim.x + threadIdx.x;
  if (t >= N_NODES * IN_C / 4) return;
  float4 v = ((const float4*)x)[t];
  ushort4 o;
  o.x = f2bf(v.x); o.y = f2bf(v.y); o.z = f2bf(v.z); o.w = f2bf(v.w);
  ((ushort4*)xb)[t] = o;
}

// ---------------------------------------------------------------------------
// CSR build step 1: 8-way REPLICATED histogram + rank. Block b updates only
// replica b&7 (one XCD per replica under round-robin dispatch) -> no
// cross-XCD line ping-pong; per-address contention /8. rank writes dense.
// ---------------------------------------------------------------------------
__global__ __launch_bounds__(256) void deg_count_kernel(
    const int* __restrict__ dst, int* __restrict__ cnt8,
    int* __restrict__ rank) {
  int e = blockIdx.x * 256 + threadIdx.x;
  if (e >= N_EDGES) return;
  int r = blockIdx.x & (N_REP - 1);
  rank[e] = atomicAdd(&cnt8[r * N_NODES + dst[e]], 1);
}

// ---------------------------------------------------------------------------
// Combine replicas: in-place exclusive scan across r per node
// (cnt8[r][g] becomes base8[r][g]); total -> cnt_tot[g].
// ---------------------------------------------------------------------------
__global__ __launch_bounds__(256) void combine_kernel(
    int* __restrict__ cnt8, int* __restrict__ cnt_tot) {
  int g = blockIdx.x * blockDim.x + threadIdx.x;
  if (g >= N_NODES) return;
  int run = 0;
#pragma unroll
  for (int r = 0; r < N_REP; ++r) {
    int v = cnt8[r * N_NODES + g];
    cnt8[r * N_NODES + g] = run;
    run += v;
  }
  cnt_tot[g] = run;
}

// ---------------------------------------------------------------------------
// CSR build step 2a: per-block inclusive scan of cnt_tot.
// ---------------------------------------------------------------------------
__global__ __launch_bounds__(SCAN_BLK) void scan1_kernel(
    const int* __restrict__ cnt, int* __restrict__ rowptr,
    int* __restrict__ partial) {
  __shared__ int s[SCAN_BLK];
  int t = threadIdx.x;
  int g = blockIdx.x * SCAN_BLK + t;
  int v = (g < N_NODES) ? cnt[g] : 0;
  s[t] = v;
  __syncthreads();
#pragma unroll
  for (int off = 1; off < SCAN_BLK; off <<= 1) {
    int u = (t >= off) ? s[t - off] : 0;
    __syncthreads();
    s[t] += u;
    __syncthreads();
  }
  if (g < N_NODES) rowptr[g + 1] = s[t];
  if (t == SCAN_BLK - 1) partial[blockIdx.x] = s[t];
}

// ---------------------------------------------------------------------------
// CSR build step 2b: exclusive scan of block totals (single block).
// ---------------------------------------------------------------------------
__global__ __launch_bounds__(128) void scan2_kernel(int* __restrict__ partial) {
  __shared__ int s[128];
  int t = threadIdx.x;
  int v = (t < N_SCAN_BLKS) ? partial[t] : 0;
  s[t] = v;
  __syncthreads();
#pragma unroll
  for (int off = 1; off < 128; off <<= 1) {
    int u = (t >= off) ? s[t - off] : 0;
    __syncthreads();
    s[t] += u;
    __syncthreads();
  }
  if (t < N_SCAN_BLKS) partial[t] = s[t] - v;  // exclusive
}

// ---------------------------------------------------------------------------
// CSR build step 2c: add block offsets -> final rowptr.
// ---------------------------------------------------------------------------
__global__ __launch_bounds__(256) void scan3_kernel(
    int* __restrict__ rowptr, const int* __restrict__ partial) {
  int i = blockIdx.x * blockDim.x + threadIdx.x;
  if (i >= N_NODES) return;
  rowptr[i + 1] += partial[i >> 10];
  if (i == 0) rowptr[0] = 0;
}

// ---------------------------------------------------------------------------
// CSR build step 3: fill csr_src — NO atomics. Placement is
// rowptr[d] + base8[r_e][d] + rank[e], r_e = (e>>8)&7 (deg_count's replica).
// XCD-partitioned for csr_src write locality.
// ---------------------------------------------------------------------------
__global__ __launch_bounds__(256) void fill_kernel(
    const int* __restrict__ src, const int* __restrict__ dst,
    const int* __restrict__ rank, const int* __restrict__ rowptr,
    const int* __restrict__ base8, int* __restrict__ csr_src) {
  int r = blockIdx.x & (N_PART - 1);
  int tid = (blockIdx.x >> 3) * 256 + threadIdx.x;
  const int stride = (PART_BLOCKS >> 3) * 256;
  int lo = r * PART_NODES, hi = lo + PART_NODES;
  for (int e = tid; e < N_EDGES; e += stride) {
    int d = dst[e];
    if (d >= lo && d < hi) {
      int re = (e >> 8) & (N_REP - 1);
      csr_src[rowptr[d] + base8[re * N_NODES + d] + rank[e]] = src[e];
    }
  }
}

// ---------------------------------------------------------------------------
// Mean aggregation layer 1 (gather of bf16 x rows, f32 accumulate).
// ---------------------------------------------------------------------------
__global__ __launch_bounds__(256) void agg_mean1_kernel(
    const unsigned short* __restrict__ xb, const int* __restrict__ rowptr,
    const int* __restrict__ csr, float* __restrict__ mean) {
  int t = blockIdx.x * blockDim.x + threadIdx.x;
  if (t >= N_NODES * (IN_C / 4)) return;
  int node = t >> 3;
  int q = t & 7;
  int p0 = rowptr[node], p1 = rowptr[node + 1];
  const ushort4* xb4 = (const ushort4*)xb;
  float ax = 0.f, ay = 0.f, az = 0.f, aw = 0.f;
  int k = p0;
  for (; k + 4 <= p1; k += 4) {
    int s0 = csr[k], s1 = csr[k + 1], s2 = csr[k + 2], s3 = csr[k + 3];
    ushort4 a = xb4[s0 * 8 + q];
    ushort4 b = xb4[s1 * 8 + q];
    ushort4 c = xb4[s2 * 8 + q];
    ushort4 d = xb4[s3 * 8 + q];
    ax += bf2f(a.x) + bf2f(b.x) + bf2f(c.x) + bf2f(d.x);
    ay += bf2f(a.y) + bf2f(b.y) + bf2f(c.y) + bf2f(d.y);
    az += bf2f(a.z) + bf2f(b.z) + bf2f(c.z) + bf2f(d.z);
    aw += bf2f(a.w) + bf2f(b.w) + bf2f(c.w) + bf2f(d.w);
  }
  for (; k < p1; ++k) {
    ushort4 a = xb4[csr[k] * 8 + q];
    ax += bf2f(a.x); ay += bf2f(a.y); az += bf2f(a.z); aw += bf2f(a.w);
  }
  float inv = 1.0f / fmaxf((float)(p1 - p0), 1.0f);
  float4 o; o.x = ax * inv; o.y = ay * inv; o.z = az * inv; o.w = aw * inv;
  ((float4*)mean)[t] = o;
}

// ---------------------------------------------------------------------------
// Mean aggregation layer 2 (gather of bf16 h1 rows, f32 accumulate).
// ---------------------------------------------------------------------------
__global__ __launch_bounds__(256) void agg_mean2_kernel(
    const unsigned short* __restrict__ hb, const int* __restrict__ rowptr,
    const int* __restrict__ csr, float* __restrict__ mean) {
  int t = blockIdx.x * blockDim.x + threadIdx.x;
  if (t >= N_NODES * (HID_C / 4)) return;
  int node = t >> 4;
  int q = t & 15;
  int p0 = rowptr[node], p1 = rowptr[node + 1];
  const ushort4* hb4 = (const ushort4*)hb;
  float ax = 0.f, ay = 0.f, az = 0.f, aw = 0.f;
  int k = p0;
  for (; k + 4 <= p1; k += 4) {
    int s0 = csr[k], s1 = csr[k + 1], s2 = csr[k + 2], s3 = csr[k + 3];
    ushort4 a = hb4[s0 * 16 + q];
    ushort4 b = hb4[s1 * 16 + q];
    ushort4 c = hb4[s2 * 16 + q];
    ushort4 d = hb4[s3 * 16 + q];
    ax += bf2f(a.x) + bf2f(b.x) + bf2f(c.x) + bf2f(d.x);
    ay += bf2f(a.y) + bf2f(b.y) + bf2f(c.y) + bf2f(d.y);
    az += bf2f(a.z) + bf2f(b.z) + bf2f(c.z) + bf2f(d.z);
    aw += bf2f(a.w) + bf2f(b.w) + bf2f(c.w) + bf2f(d.w);
  }
  for (; k < p1; ++k) {
    ushort4 a = hb4[csr[k] * 16 + q];
    ax += bf2f(a.x); ay += bf2f(a.y); az += bf2f(a.z); aw += bf2f(a.w);
  }
  float inv = 1.0f / fmaxf((float)(p1 - p0), 1.0f);
  float4 o; o.x = ax * inv; o.y = ay * inv; o.z = az * inv; o.w = aw * inv;
  ((float4*)mean)[t] = o;
}

// ---------------------------------------------------------------------------
// Layer 1 tiled GEMM; epilogue writes h1 (f32) AND h1b (bf16).
// ---------------------------------------------------------------------------
__global__ __launch_bounds__(256) void layer1_gemm_kernel(
    const float* __restrict__ x, const float* __restrict__ mean,
    const float* __restrict__ Wl, const float* __restrict__ bl,
    const float* __restrict__ Wr, float* __restrict__ h1,
    unsigned short* __restrict__ h1b) {
  const int LD = 17;  // float4 row stride (16 data + 1 pad)
  __shared__ float4 sA[64 * LD];
  __shared__ float4 sB[64 * LD];
  __shared__ float sbias[64];
  int tid = threadIdx.x;
  int base = blockIdx.x * 64;
  const float4* mean4 = (const float4*)mean;
  const float4* x4 = (const float4*)x;
  const float4* Wl4 = (const float4*)Wl;
  const float4* Wr4 = (const float4*)Wr;
  const float4 zero = make_float4(0.f, 0.f, 0.f, 0.f);
  for (int idx = tid; idx < 64 * 16; idx += 256) {
    int row = idx >> 4, col = idx & 15;
    int node = base + row;
    float4 v = zero;
    if (node < N_NODES)
      v = (col < 8) ? mean4[node * 8 + col] : x4[node * 8 + (col - 8)];
    sA[row * LD + col] = v;
    sB[row * LD + col] = (col < 8) ? Wl4[row * 8 + col] : Wr4[row * 8 + (col - 8)];
  }
  if (tid < 64) sbias[tid] = bl[tid];
  __syncthreads();

  int tn = tid & 15;
  int to = tid >> 4;
  float acc[4][4];
#pragma unroll
  for (int i = 0; i < 4; ++i)
#pragma unroll
    for (int j = 0; j < 4; ++j) acc[i][j] = 0.f;

#pragma unroll 4
  for (int k4 = 0; k4 < 16; ++k4) {
    float4 a[4], b[4];
#pragma unroll
    for (int i = 0; i < 4; ++i) a[i] = sA[(tn + i * 16) * LD + k4];
#pragma unroll
    for (int j = 0; j < 4; ++j) b[j] = sB[(to * 4 + j) * LD + k4];
#pragma unroll
    for (int i = 0; i < 4; ++i)
#pragma unroll
      for (int j = 0; j < 4; ++j) {
        acc[i][j] = fmaf(a[i].x, b[j].x, acc[i][j]);
        acc[i][j] = fmaf(a[i].y, b[j].y, acc[i][j]);
        acc[i][j] = fmaf(a[i].z, b[j].z, acc[i][j]);
        acc[i][j] = fmaf(a[i].w, b[j].w, acc[i][j]);
      }
  }

  float4* h14 = (float4*)h1;
  ushort4* h1b4 = (ushort4*)h1b;
#pragma unroll
  for (int i = 0; i < 4; ++i) {
    int node = base + tn + i * 16;
    if (node < N_NODES) {
      float4 v;
      v.x = fmaxf(acc[i][0] + sbias[to * 4 + 0], 0.f);
      v.y = fmaxf(acc[i][1] + sbias[to * 4 + 1], 0.f);
      v.z = fmaxf(acc[i][2] + sbias[to * 4 + 2], 0.f);
      v.w = fmaxf(acc[i][3] + sbias[to * 4 + 3], 0.f);
      h14[node * 16 + to] = v;
      ushort4 hb;
      hb.x = f2bf(v.x); hb.y = f2bf(v.y); hb.z = f2bf(v.z); hb.w = f2bf(v.w);
      h1b4[node * 16 + to] = hb;
    }
  }
}

// ---------------------------------------------------------------------------
// Layer 2 + head fused.
// ---------------------------------------------------------------------------
__global__ __launch_bounds__(256) void layer2_head_kernel(
    const float* __restrict__ h1, const float* __restrict__ mean,
    const float* __restrict__ Wl, const float* __restrict__ bl,
    const float* __restrict__ Wr,
    const float* __restrict__ Wlin, const float* __restrict__ blin,
    float* __restrict__ out) {
  const int LD = 33;  // float4 row stride (32 data + 1 pad)
  __shared__ float4 sA[64 * LD];
  __shared__ float4 sB[64 * LD];
  __shared__ float sbias[64];
  __shared__ float sWlin[OUT_C * 64];
  __shared__ float sblin[OUT_C];
  int tid = threadIdx.x;
  int base = blockIdx.x * 64;
  const float4* mean4 = (const float4*)mean;
  const float4* h14 = (const float4*)h1;
  const float4* Wl4 = (const float4*)Wl;
  const float4* Wr4 = (const float4*)Wr;
  const float4 zero = make_float4(0.f, 0.f, 0.f, 0.f);
  for (int idx = tid; idx < 64 * 32; idx += 256) {
    int row = idx >> 5, col = idx & 31;
    int node = base + row;
    float4 v = zero;
    if (node < N_NODES)
      v = (col < 16) ? mean4[node * 16 + col] : h14[node * 16 + (col - 16)];
    sA[row * LD + col] = v;
    sB[row * LD + col] = (col < 16) ? Wl4[row * 16 + col] : Wr4[row * 16 + (col - 16)];
  }
  if (tid < 64) sbias[tid] = bl[tid];
  for (int i = tid; i < OUT_C * 64; i += 256) sWlin[i] = Wlin[i];
  if (tid < OUT_C) sblin[tid] = blin[tid];
  __syncthreads();

  int tn = tid & 15;
  int to = tid >> 4;
  float acc[4][4];
#pragma unroll
  for (int i = 0; i < 4; ++i)
#pragma unroll
    for (int j = 0; j < 4; ++j) acc[i][j] = 0.f;

#pragma unroll 4
  for (int k4 = 0; k4 < 32; ++k4) {
    float4 a[4], b[4];
#pragma unroll
    for (int i = 0; i < 4; ++i) a[i] = sA[(tn + i * 16) * LD + k4];
#pragma unroll
    for (int j = 0; j < 4; ++j) b[j] = sB[(to * 4 + j) * LD + k4];
#pragma unroll
    for (int i = 0; i < 4; ++i)
#pragma unroll
      for (int j = 0; j < 4; ++j) {
        acc[i][j] = fmaf(a[i].x, b[j].x, acc[i][j]);
        acc[i][j] = fmaf(a[i].y, b[j].y, acc[i][j]);
        acc[i][j] = fmaf(a[i].z, b[j].z, acc[i][j]);
        acc[i][j] = fmaf(a[i].w, b[j].w, acc[i][j]);
      }
  }

  __syncthreads();
  float* sH = (float*)sA;
  const int LDH = 69;
#pragma unroll
  for (int i = 0; i < 4; ++i) {
    int r = tn + i * 16;
#pragma unroll
    for (int j = 0; j < 4; ++j) {
      sH[r * LDH + to * 4 + j] = fmaxf(acc[i][j] + sbias[to * 4 + j], 0.f);
    }
  }
  __syncthreads();

  if (tid < 64) {
    int node = base + tid;
    if (node < N_NODES) {
      float o5[OUT_C];
#pragma unroll
      for (int m = 0; m < OUT_C; ++m) o5[m] = sblin[m];
      const float* hr = &sH[tid * LDH];
#pragma unroll 8
      for (int c = 0; c < HID_C; ++c) {
        float v = hr[c];
#pragma unroll
        for (int m = 0; m < OUT_C; ++m) o5[m] = fmaf(v, sWlin[m * 64 + c], o5[m]);
      }
#pragma unroll
      for (int m = 0; m < OUT_C; ++m) out[node * OUT_C + m] = o5[m];
    }
  }
}

extern "C" void kernel_launch(void* const* d_in, const int* in_sizes, int n_in,
                              void* d_out, int out_size, void* d_ws, size_t ws_size,
                              hipStream_t stream) {
  const float* x    = (const float*)d_in[0];
  const int*   ei   = (const int*)d_in[1];
  const float* W1l  = (const float*)d_in[2];
  const float* b1   = (const float*)d_in[3];
  const float* W1r  = (const float*)d_in[4];
  const float* W2l  = (const float*)d_in[5];
  const float* b2   = (const float*)d_in[6];
  const float* W2r  = (const float*)d_in[7];
  const float* Wlin = (const float*)d_in[8];
  const float* blin = (const float*)d_in[9];

  const int* src = ei;
  const int* dst = ei + N_EDGES;

  // Workspace layout (4B units):
  //   rowptr  [100004]
  //   cnt8    [8*100000]  (replicated histogram -> becomes base8 after combine)
  //   cnt_tot [100000]
  //   partial [128]
  //   rank    [1600000]   (per-edge rank within its replica's dst count)
  //   csr_src [1600000]
  //   xb      [N*32/2]    (bf16 x)
  //   h1b     [N*64/2]    (bf16 h1)
  //   mean    [N*64]
  //   h1      [N*64]
  int* rowptr  = (int*)d_ws;
  int* cnt8    = rowptr + 100004;
  int* cnt_tot = cnt8 + N_REP * N_NODES;
  int* partial = cnt_tot + N_NODES;
  int* rank    = partial + 128;
  int* csr_src = rank + N_EDGES;
  unsigned short* xb  = (unsigned short*)(csr_src + N_EDGES);
  unsigned short* h1b = xb + (size_t)N_NODES * IN_C;
  float* mean  = (float*)(h1b + (size_t)N_NODES * HID_C);
  float* h1    = mean + (size_t)N_NODES * HID_C;

  hipMemsetAsync(cnt8, 0, (size_t)N_REP * N_NODES * sizeof(int), stream);

  convert_x_kernel<<<(N_NODES * IN_C / 4 + 255) / 256, 256, 0, stream>>>(x, xb);
  deg_count_kernel<<<(N_EDGES + 255) / 256, 256, 0, stream>>>(dst, cnt8, rank);
  combine_kernel<<<(N_NODES + 255) / 256, 256, 0, stream>>>(cnt8, cnt_tot);
  scan1_kernel<<<N_SCAN_BLKS, SCAN_BLK, 0, stream>>>(cnt_tot, rowptr, partial);
  scan2_kernel<<<1, 128, 0, stream>>>(partial);
  scan3_kernel<<<(N_NODES + 255) / 256, 256, 0, stream>>>(rowptr, partial);
  fill_kernel<<<PART_BLOCKS, 256, 0, stream>>>(src, dst, rank, rowptr, cnt8, csr_src);

  agg_mean1_kernel<<<(N_NODES * (IN_C / 4) + 255) / 256, 256, 0, stream>>>(
      xb, rowptr, csr_src, mean);
  layer1_gemm_kernel<<<N_TILES, 256, 0, stream>>>(
      x, mean, W1l, b1, W1r, h1, h1b);
  agg_mean2_kernel<<<(N_NODES * (HID_C / 4) + 255) / 256, 256, 0, stream>>>(
      h1b, rowptr, csr_src, mean);
  layer2_head_kernel<<<N_TILES, 256, 0, stream>>>(
      h1, mean, W2l, b2, W2r, Wlin, blin, (float*)d_out);
}

// Round 20
// 210.139 us; speedup vs baseline: 1.2728x; 1.2728x over previous
//
#include <hip/hip_runtime.h>

#define N_NODES 100000
#define IN_C 32
#define HID_C 64
#define OUT_C 5
#define N_EDGES 1600000
#define N_TILES ((N_NODES + 63) / 64)   // 1563

// Bucketed CSR build: 196 buckets of 512 nodes; per-edge atomics in LDS only.
#define BKT_SHIFT 9
#define BKT_NODES 512
#define NBKT 196                         // ceil(100000/512)
#define BKT_CAP 10240                    // mean 8163, +23 sigma
#define P1_CHUNK 4096
#define NP1 ((N_EDGES + P1_CHUNK - 1) / P1_CHUNK)   // 391

__device__ __forceinline__ unsigned short f2bf(float f) {
  unsigned int u = __float_as_uint(f);
  unsigned int r = (u + 0x7FFFu + ((u >> 16) & 1u)) >> 16;  // RNE
  return (unsigned short)r;
}
__device__ __forceinline__ float bf2f(unsigned short b) {
  return __uint_as_float(((unsigned int)b) << 16);
}

// ---------------------------------------------------------------------------
// Convert x (f32 [N,32]) -> xb (bf16).
// ---------------------------------------------------------------------------
__global__ __launch_bounds__(256) void convert_x_kernel(
    const float* __restrict__ x, unsigned short* __restrict__ xb) {
  int t = blockIdx.x * blockDim.x + threadIdx.x;
  if (t >= N_NODES * IN_C / 4) return;
  float4 v = ((const float4*)x)[t];
  ushort4 o;
  o.x = f2bf(v.x); o.y = f2bf(v.y); o.z = f2bf(v.z); o.w = f2bf(v.w);
  ((ushort4*)xb)[t] = o;
}

// ---------------------------------------------------------------------------
// Pass 1: bin edges into 196 dst-buckets. Per-edge atomics are LDS-only;
// global returning atomics: 196 per block (space reservation), 20x fewer
// than per-edge. LDS = ~3 KB -> full occupancy (R8's bin died at 51 KB).
// rec = (dst & 511) << 17 | src  (26 bits).
// ---------------------------------------------------------------------------
__global__ __launch_bounds__(256) void p1_bin_kernel(
    const int* __restrict__ src, const int* __restrict__ dst,
    unsigned int* __restrict__ region, int* __restrict__ bucket_cur) {
  __shared__ int lhist[NBKT];
  __shared__ int gbase[NBKT];
  int tid = threadIdx.x;
  for (int i = tid; i < NBKT; i += 256) lhist[i] = 0;
  __syncthreads();
  int e0 = blockIdx.x * P1_CHUNK;
  for (int i = tid; i < P1_CHUNK; i += 256) {
    int e = e0 + i;
    if (e < N_EDGES) atomicAdd(&lhist[dst[e] >> BKT_SHIFT], 1);
  }
  __syncthreads();
  for (int i = tid; i < NBKT; i += 256) {
    int c = lhist[i];
    gbase[i] = (c > 0) ? atomicAdd(&bucket_cur[i], c) : 0;
    lhist[i] = 0;  // reuse as local cursor
  }
  __syncthreads();
  for (int i = tid; i < P1_CHUNK; i += 256) {
    int e = e0 + i;
    if (e < N_EDGES) {
      int d = dst[e];
      int b = d >> BKT_SHIFT;
      unsigned int rec =
          ((unsigned int)(d & (BKT_NODES - 1)) << 17) | (unsigned int)src[e];
      int slot = atomicAdd(&lhist[b], 1);
      int pos = gbase[b] + slot;
      if (pos < BKT_CAP) region[(size_t)b * BKT_CAP + pos] = rec;
    }
  }
}

// ---------------------------------------------------------------------------
// Scan of 196 bucket counts -> bucket_base; rowptr[N] = total.
// ---------------------------------------------------------------------------
__global__ __launch_bounds__(256) void bucket_scan_kernel(
    const int* __restrict__ bucket_cur, int* __restrict__ bucket_base,
    int* __restrict__ rowptr) {
  __shared__ int s[2][256];
  int t = threadIdx.x;
  int v = 0;
  if (t < NBKT) { v = bucket_cur[t]; if (v > BKT_CAP) v = BKT_CAP; }
  s[0][t] = v;
  __syncthreads();
  int pin = 0;
#pragma unroll
  for (int off = 1; off < 256; off <<= 1) {
    int u = s[pin][t];
    if (t >= off) u += s[pin][t - off];
    s[pin ^ 1][t] = u;
    __syncthreads();
    pin ^= 1;
  }
  if (t < NBKT) bucket_base[t] = s[pin][t] - v;  // exclusive
  if (t == 0) rowptr[N_NODES] = s[pin][NBKT - 1];
}

// ---------------------------------------------------------------------------
// Pass 2: one block per bucket. LDS histogram(512) + scan + LDS-atomic
// placement. Writes rowptr (coalesced) and csr_src (contiguous ~32 KB
// window per bucket). No global atomics at all.
// ---------------------------------------------------------------------------
__global__ __launch_bounds__(256) void p2_csr_kernel(
    const unsigned int* __restrict__ region, const int* __restrict__ bucket_cur,
    const int* __restrict__ bucket_base, int* __restrict__ rowptr,
    int* __restrict__ csr_src) {
  __shared__ int hist[BKT_NODES];
  __shared__ int sc[2][BKT_NODES];
  int tid = threadIdx.x;
  int b = blockIdx.x;
  int n = bucket_cur[b]; if (n > BKT_CAP) n = BKT_CAP;
  int base = bucket_base[b];
  int node0 = b << BKT_SHIFT;
  const unsigned int* reg = region + (size_t)b * BKT_CAP;

  for (int i = tid; i < BKT_NODES; i += 256) hist[i] = 0;
  __syncthreads();
  for (int i = tid; i < n; i += 256) atomicAdd(&hist[reg[i] >> 17], 1);
  __syncthreads();
  for (int i = tid; i < BKT_NODES; i += 256) sc[0][i] = hist[i];
  __syncthreads();
  int pin = 0;
#pragma unroll
  for (int off = 1; off < BKT_NODES; off <<= 1) {
    for (int i = tid; i < BKT_NODES; i += 256) {
      int v = sc[pin][i];
      if (i >= off) v += sc[pin][i - off];
      sc[pin ^ 1][i] = v;
    }
    __syncthreads();
    pin ^= 1;
  }
  for (int i = tid; i < BKT_NODES; i += 256) {
    int excl = sc[pin][i] - hist[i];
    hist[i] = excl;  // reuse as cursor
    int g = node0 + i;
    if (g < N_NODES) rowptr[g] = base + excl;
  }
  __syncthreads();
  for (int i = tid; i < n; i += 256) {
    unsigned int rec = reg[i];
    int slot = atomicAdd(&hist[rec >> 17], 1);
    csr_src[base + slot] = (int)(rec & 0x1FFFFu);
  }
}

// ---------------------------------------------------------------------------
// Mean aggregation layer 1 (gather of bf16 x rows, f32 accumulate).
// ---------------------------------------------------------------------------
__global__ __launch_bounds__(256) void agg_mean1_kernel(
    const unsigned short* __restrict__ xb, const int* __restrict__ rowptr,
    const int* __restrict__ csr, float* __restrict__ mean) {
  int t = blockIdx.x * blockDim.x + threadIdx.x;
  if (t >= N_NODES * (IN_C / 4)) return;
  int node = t >> 3;
  int q = t & 7;
  int p0 = rowptr[node], p1 = rowptr[node + 1];
  const ushort4* xb4 = (const ushort4*)xb;
  float ax = 0.f, ay = 0.f, az = 0.f, aw = 0.f;
  int k = p0;
  for (; k + 4 <= p1; k += 4) {
    int s0 = csr[k], s1 = csr[k + 1], s2 = csr[k + 2], s3 = csr[k + 3];
    ushort4 a = xb4[s0 * 8 + q];
    ushort4 b = xb4[s1 * 8 + q];
    ushort4 c = xb4[s2 * 8 + q];
    ushort4 d = xb4[s3 * 8 + q];
    ax += bf2f(a.x) + bf2f(b.x) + bf2f(c.x) + bf2f(d.x);
    ay += bf2f(a.y) + bf2f(b.y) + bf2f(c.y) + bf2f(d.y);
    az += bf2f(a.z) + bf2f(b.z) + bf2f(c.z) + bf2f(d.z);
    aw += bf2f(a.w) + bf2f(b.w) + bf2f(c.w) + bf2f(d.w);
  }
  for (; k < p1; ++k) {
    ushort4 a = xb4[csr[k] * 8 + q];
    ax += bf2f(a.x); ay += bf2f(a.y); az += bf2f(a.z); aw += bf2f(a.w);
  }
  float inv = 1.0f / fmaxf((float)(p1 - p0), 1.0f);
  float4 o; o.x = ax * inv; o.y = ay * inv; o.z = az * inv; o.w = aw * inv;
  ((float4*)mean)[t] = o;
}

// ---------------------------------------------------------------------------
// Mean aggregation layer 2 (gather of bf16 h1 rows, f32 accumulate).
// ---------------------------------------------------------------------------
__global__ __launch_bounds__(256) void agg_mean2_kernel(
    const unsigned short* __restrict__ hb, const int* __restrict__ rowptr,
    const int* __restrict__ csr, float* __restrict__ mean) {
  int t = blockIdx.x * blockDim.x + threadIdx.x;
  if (t >= N_NODES * (HID_C / 4)) return;
  int node = t >> 4;
  int q = t & 15;
  int p0 = rowptr[node], p1 = rowptr[node + 1];
  const ushort4* hb4 = (const ushort4*)hb;
  float ax = 0.f, ay = 0.f, az = 0.f, aw = 0.f;
  int k = p0;
  for (; k + 4 <= p1; k += 4) {
    int s0 = csr[k], s1 = csr[k + 1], s2 = csr[k + 2], s3 = csr[k + 3];
    ushort4 a = hb4[s0 * 16 + q];
    ushort4 b = hb4[s1 * 16 + q];
    ushort4 c = hb4[s2 * 16 + q];
    ushort4 d = hb4[s3 * 16 + q];
    ax += bf2f(a.x) + bf2f(b.x) + bf2f(c.x) + bf2f(d.x);
    ay += bf2f(a.y) + bf2f(b.y) + bf2f(c.y) + bf2f(d.y);
    az += bf2f(a.z) + bf2f(b.z) + bf2f(c.z) + bf2f(d.z);
    aw += bf2f(a.w) + bf2f(b.w) + bf2f(c.w) + bf2f(d.w);
  }
  for (; k < p1; ++k) {
    ushort4 a = hb4[csr[k] * 16 + q];
    ax += bf2f(a.x); ay += bf2f(a.y); az += bf2f(a.z); aw += bf2f(a.w);
  }
  float inv = 1.0f / fmaxf((float)(p1 - p0), 1.0f);
  float4 o; o.x = ax * inv; o.y = ay * inv; o.z = az * inv; o.w = aw * inv;
  ((float4*)mean)[t] = o;
}

// ---------------------------------------------------------------------------
// Layer 1 tiled GEMM; epilogue writes h1 (f32) AND h1b (bf16).
// ---------------------------------------------------------------------------
__global__ __launch_bounds__(256) void layer1_gemm_kernel(
    const float* __restrict__ x, const float* __restrict__ mean,
    const float* __restrict__ Wl, const float* __restrict__ bl,
    const float* __restrict__ Wr, float* __restrict__ h1,
    unsigned short* __restrict__ h1b) {
  const int LD = 17;  // float4 row stride (16 data + 1 pad)
  __shared__ float4 sA[64 * LD];
  __shared__ float4 sB[64 * LD];
  __shared__ float sbias[64];
  int tid = threadIdx.x;
  int base = blockIdx.x * 64;
  const float4* mean4 = (const float4*)mean;
  const float4* x4 = (const float4*)x;
  const float4* Wl4 = (const float4*)Wl;
  const float4* Wr4 = (const float4*)Wr;
  const float4 zero = make_float4(0.f, 0.f, 0.f, 0.f);
  for (int idx = tid; idx < 64 * 16; idx += 256) {
    int row = idx >> 4, col = idx & 15;
    int node = base + row;
    float4 v = zero;
    if (node < N_NODES)
      v = (col < 8) ? mean4[node * 8 + col] : x4[node * 8 + (col - 8)];
    sA[row * LD + col] = v;
    sB[row * LD + col] = (col < 8) ? Wl4[row * 8 + col] : Wr4[row * 8 + (col - 8)];
  }
  if (tid < 64) sbias[tid] = bl[tid];
  __syncthreads();

  int tn = tid & 15;
  int to = tid >> 4;
  float acc[4][4];
#pragma unroll
  for (int i = 0; i < 4; ++i)
#pragma unroll
    for (int j = 0; j < 4; ++j) acc[i][j] = 0.f;

#pragma unroll 4
  for (int k4 = 0; k4 < 16; ++k4) {
    float4 a[4], b[4];
#pragma unroll
    for (int i = 0; i < 4; ++i) a[i] = sA[(tn + i * 16) * LD + k4];
#pragma unroll
    for (int j = 0; j < 4; ++j) b[j] = sB[(to * 4 + j) * LD + k4];
#pragma unroll
    for (int i = 0; i < 4; ++i)
#pragma unroll
      for (int j = 0; j < 4; ++j) {
        acc[i][j] = fmaf(a[i].x, b[j].x, acc[i][j]);
        acc[i][j] = fmaf(a[i].y, b[j].y, acc[i][j]);
        acc[i][j] = fmaf(a[i].z, b[j].z, acc[i][j]);
        acc[i][j] = fmaf(a[i].w, b[j].w, acc[i][j]);
      }
  }

  float4* h14 = (float4*)h1;
  ushort4* h1b4 = (ushort4*)h1b;
#pragma unroll
  for (int i = 0; i < 4; ++i) {
    int node = base + tn + i * 16;
    if (node < N_NODES) {
      float4 v;
      v.x = fmaxf(acc[i][0] + sbias[to * 4 + 0], 0.f);
      v.y = fmaxf(acc[i][1] + sbias[to * 4 + 1], 0.f);
      v.z = fmaxf(acc[i][2] + sbias[to * 4 + 2], 0.f);
      v.w = fmaxf(acc[i][3] + sbias[to * 4 + 3], 0.f);
      h14[node * 16 + to] = v;
      ushort4 hb;
      hb.x = f2bf(v.x); hb.y = f2bf(v.y); hb.z = f2bf(v.z); hb.w = f2bf(v.w);
      h1b4[node * 16 + to] = hb;
    }
  }
}

// ---------------------------------------------------------------------------
// Layer 2 + head fused.
// ---------------------------------------------------------------------------
__global__ __launch_bounds__(256) void layer2_head_kernel(
    const float* __restrict__ h1, const float* __restrict__ mean,
    const float* __restrict__ Wl, const float* __restrict__ bl,
    const float* __restrict__ Wr,
    const float* __restrict__ Wlin, const float* __restrict__ blin,
    float* __restrict__ out) {
  const int LD = 33;  // float4 row stride (32 data + 1 pad)
  __shared__ float4 sA[64 * LD];
  __shared__ float4 sB[64 * LD];
  __shared__ float sbias[64];
  __shared__ float sWlin[OUT_C * 64];
  __shared__ float sblin[OUT_C];
  int tid = threadIdx.x;
  int base = blockIdx.x * 64;
  const float4* mean4 = (const float4*)mean;
  const float4* h14 = (const float4*)h1;
  const float4* Wl4 = (const float4*)Wl;
  const float4* Wr4 = (const float4*)Wr;
  const float4 zero = make_float4(0.f, 0.f, 0.f, 0.f);
  for (int idx = tid; idx < 64 * 32; idx += 256) {
    int row = idx >> 5, col = idx & 31;
    int node = base + row;
    float4 v = zero;
    if (node < N_NODES)
      v = (col < 16) ? mean4[node * 16 + col] : h14[node * 16 + (col - 16)];
    sA[row * LD + col] = v;
    sB[row * LD + col] = (col < 16) ? Wl4[row * 16 + col] : Wr4[row * 16 + (col - 16)];
  }
  if (tid < 64) sbias[tid] = bl[tid];
  for (int i = tid; i < OUT_C * 64; i += 256) sWlin[i] = Wlin[i];
  if (tid < OUT_C) sblin[tid] = blin[tid];
  __syncthreads();

  int tn = tid & 15;
  int to = tid >> 4;
  float acc[4][4];
#pragma unroll
  for (int i = 0; i < 4; ++i)
#pragma unroll
    for (int j = 0; j < 4; ++j) acc[i][j] = 0.f;

#pragma unroll 4
  for (int k4 = 0; k4 < 32; ++k4) {
    float4 a[4], b[4];
#pragma unroll
    for (int i = 0; i < 4; ++i) a[i] = sA[(tn + i * 16) * LD + k4];
#pragma unroll
    for (int j = 0; j < 4; ++j) b[j] = sB[(to * 4 + j) * LD + k4];
#pragma unroll
    for (int i = 0; i < 4; ++i)
#pragma unroll
      for (int j = 0; j < 4; ++j) {
        acc[i][j] = fmaf(a[i].x, b[j].x, acc[i][j]);
        acc[i][j] = fmaf(a[i].y, b[j].y, acc[i][j]);
        acc[i][j] = fmaf(a[i].z, b[j].z, acc[i][j]);
        acc[i][j] = fmaf(a[i].w, b[j].w, acc[i][j]);
      }
  }

  __syncthreads();
  float* sH = (float*)sA;
  const int LDH = 69;
#pragma unroll
  for (int i = 0; i < 4; ++i) {
    int r = tn + i * 16;
#pragma unroll
    for (int j = 0; j < 4; ++j) {
      sH[r * LDH + to * 4 + j] = fmaxf(acc[i][j] + sbias[to * 4 + j], 0.f);
    }
  }
  __syncthreads();

  if (tid < 64) {
    int node = base + tid;
    if (node < N_NODES) {
      float o5[OUT_C];
#pragma unroll
      for (int m = 0; m < OUT_C; ++m) o5[m] = sblin[m];
      const float* hr = &sH[tid * LDH];
#pragma unroll 8
      for (int c = 0; c < HID_C; ++c) {
        float v = hr[c];
#pragma unroll
        for (int m = 0; m < OUT_C; ++m) o5[m] = fmaf(v, sWlin[m * 64 + c], o5[m]);
      }
#pragma unroll
      for (int m = 0; m < OUT_C; ++m) out[node * OUT_C + m] = o5[m];
    }
  }
}

extern "C" void kernel_launch(void* const* d_in, const int* in_sizes, int n_in,
                              void* d_out, int out_size, void* d_ws, size_t ws_size,
                              hipStream_t stream) {
  const float* x    = (const float*)d_in[0];
  const int*   ei   = (const int*)d_in[1];
  const float* W1l  = (const float*)d_in[2];
  const float* b1   = (const float*)d_in[3];
  const float* W1r  = (const float*)d_in[4];
  const float* W2l  = (const float*)d_in[5];
  const float* b2   = (const float*)d_in[6];
  const float* W2r  = (const float*)d_in[7];
  const float* Wlin = (const float*)d_in[8];
  const float* blin = (const float*)d_in[9];

  const int* src = ei;
  const int* dst = ei + N_EDGES;

  // Workspace layout (4B units):
  //   rowptr      [100004]
  //   bucket_cur  [256]
  //   bucket_base [256]
  //   region      [196*10240 ≈ 2.01M u32 = 8.0 MB]
  //   csr_src     [1600000]
  //   xb          [N*32/2]  (bf16 x)
  //   h1b         [N*64/2]  (bf16 h1)
  //   mean        [N*64]
  //   h1          [N*64]
  int* rowptr       = (int*)d_ws;
  int* bucket_cur   = rowptr + 100004;
  int* bucket_base  = bucket_cur + 256;
  unsigned int* region = (unsigned int*)(bucket_base + 256);
  int* csr_src      = (int*)(region + (size_t)NBKT * BKT_CAP);
  unsigned short* xb  = (unsigned short*)(csr_src + N_EDGES);
  unsigned short* h1b = xb + (size_t)N_NODES * IN_C;
  float* mean  = (float*)(h1b + (size_t)N_NODES * HID_C);
  float* h1    = mean + (size_t)N_NODES * HID_C;

  hipMemsetAsync(bucket_cur, 0, 256 * sizeof(int), stream);

  convert_x_kernel<<<(N_NODES * IN_C / 4 + 255) / 256, 256, 0, stream>>>(x, xb);
  p1_bin_kernel<<<NP1, 256, 0, stream>>>(src, dst, region, bucket_cur);
  bucket_scan_kernel<<<1, 256, 0, stream>>>(bucket_cur, bucket_base, rowptr);
  p2_csr_kernel<<<NBKT, 256, 0, stream>>>(region, bucket_cur, bucket_base,
                                          rowptr, csr_src);

  agg_mean1_kernel<<<(N_NODES * (IN_C / 4) + 255) / 256, 256, 0, stream>>>(
      xb, rowptr, csr_src, mean);
  layer1_gemm_kernel<<<N_TILES, 256, 0, stream>>>(
      x, mean, W1l, b1, W1r, h1, h1b);
  agg_mean2_kernel<<<(N_NODES * (HID_C / 4) + 255) / 256, 256, 0, stream>>>(
      h1b, rowptr, csr_src, mean);
  layer2_head_kernel<<<N_TILES, 256, 0, stream>>>(
      h1, mean, W2l, b2, W2r, Wlin, blin, (float*)d_out);
}

// Round 21
// 201.398 us; speedup vs baseline: 1.3280x; 1.0434x over previous
//
#include <hip/hip_runtime.h>

#define N_NODES 100000
#define IN_C 32
#define HID_C 64
#define OUT_C 5
#define N_EDGES 1600000
#define N_TILES ((N_NODES + 63) / 64)   // 1563

// Bucketed CSR build: 196 buckets of 512 nodes; per-edge atomics in LDS only.
#define BKT_SHIFT 9
#define BKT_NODES 512
#define NBKT 196                         // ceil(100000/512)
#define BKT_CAP 10240                    // mean 8163, +23 sigma
#define P1_CHUNK 4096
#define NP1 ((N_EDGES + P1_CHUNK - 1) / P1_CHUNK)   // 391

__device__ __forceinline__ unsigned short f2bf(float f) {
  unsigned int u = __float_as_uint(f);
  unsigned int r = (u + 0x7FFFu + ((u >> 16) & 1u)) >> 16;  // RNE
  return (unsigned short)r;
}
__device__ __forceinline__ float bf2f(unsigned short b) {
  return __uint_as_float(((unsigned int)b) << 16);
}
// unpack a uint32 holding two bf16 (lo | hi<<16) into two floats
#define UNPK2(u, f0, f1)                         \
  {                                              \
    f0 = __uint_as_float((u) << 16);             \
    f1 = __uint_as_float((u) & 0xFFFF0000u);     \
  }

// ---------------------------------------------------------------------------
// Convert x (f32 [N,32]) -> xb (bf16).
// ---------------------------------------------------------------------------
__global__ __launch_bounds__(256) void convert_x_kernel(
    const float* __restrict__ x, unsigned short* __restrict__ xb) {
  int t = blockIdx.x * blockDim.x + threadIdx.x;
  if (t >= N_NODES * IN_C / 4) return;
  float4 v = ((const float4*)x)[t];
  ushort4 o;
  o.x = f2bf(v.x); o.y = f2bf(v.y); o.z = f2bf(v.z); o.w = f2bf(v.w);
  ((ushort4*)xb)[t] = o;
}

// ---------------------------------------------------------------------------
// Pass 1: bin edges into 196 dst-buckets (LDS-only per-edge atomics).
// ---------------------------------------------------------------------------
__global__ __launch_bounds__(256) void p1_bin_kernel(
    const int* __restrict__ src, const int* __restrict__ dst,
    unsigned int* __restrict__ region, int* __restrict__ bucket_cur) {
  __shared__ int lhist[NBKT];
  __shared__ int gbase[NBKT];
  int tid = threadIdx.x;
  for (int i = tid; i < NBKT; i += 256) lhist[i] = 0;
  __syncthreads();
  int e0 = blockIdx.x * P1_CHUNK;
  for (int i = tid; i < P1_CHUNK; i += 256) {
    int e = e0 + i;
    if (e < N_EDGES) atomicAdd(&lhist[dst[e] >> BKT_SHIFT], 1);
  }
  __syncthreads();
  for (int i = tid; i < NBKT; i += 256) {
    int c = lhist[i];
    gbase[i] = (c > 0) ? atomicAdd(&bucket_cur[i], c) : 0;
    lhist[i] = 0;  // reuse as local cursor
  }
  __syncthreads();
  for (int i = tid; i < P1_CHUNK; i += 256) {
    int e = e0 + i;
    if (e < N_EDGES) {
      int d = dst[e];
      int b = d >> BKT_SHIFT;
      unsigned int rec =
          ((unsigned int)(d & (BKT_NODES - 1)) << 17) | (unsigned int)src[e];
      int slot = atomicAdd(&lhist[b], 1);
      int pos = gbase[b] + slot;
      if (pos < BKT_CAP) region[(size_t)b * BKT_CAP + pos] = rec;
    }
  }
}

// ---------------------------------------------------------------------------
// Scan of 196 bucket counts -> bucket_base; rowptr[N] = total.
// ---------------------------------------------------------------------------
__global__ __launch_bounds__(256) void bucket_scan_kernel(
    const int* __restrict__ bucket_cur, int* __restrict__ bucket_base,
    int* __restrict__ rowptr) {
  __shared__ int s[2][256];
  int t = threadIdx.x;
  int v = 0;
  if (t < NBKT) { v = bucket_cur[t]; if (v > BKT_CAP) v = BKT_CAP; }
  s[0][t] = v;
  __syncthreads();
  int pin = 0;
#pragma unroll
  for (int off = 1; off < 256; off <<= 1) {
    int u = s[pin][t];
    if (t >= off) u += s[pin][t - off];
    s[pin ^ 1][t] = u;
    __syncthreads();
    pin ^= 1;
  }
  if (t < NBKT) bucket_base[t] = s[pin][t] - v;  // exclusive
  if (t == 0) rowptr[N_NODES] = s[pin][NBKT - 1];
}

// ---------------------------------------------------------------------------
// Pass 2: per-bucket LDS histogram + scan + placement; coalesced writes.
// ---------------------------------------------------------------------------
__global__ __launch_bounds__(256) void p2_csr_kernel(
    const unsigned int* __restrict__ region, const int* __restrict__ bucket_cur,
    const int* __restrict__ bucket_base, int* __restrict__ rowptr,
    int* __restrict__ csr_src) {
  __shared__ int hist[BKT_NODES];
  __shared__ int sc[2][BKT_NODES];
  int tid = threadIdx.x;
  int b = blockIdx.x;
  int n = bucket_cur[b]; if (n > BKT_CAP) n = BKT_CAP;
  int base = bucket_base[b];
  int node0 = b << BKT_SHIFT;
  const unsigned int* reg = region + (size_t)b * BKT_CAP;

  for (int i = tid; i < BKT_NODES; i += 256) hist[i] = 0;
  __syncthreads();
  for (int i = tid; i < n; i += 256) atomicAdd(&hist[reg[i] >> 17], 1);
  __syncthreads();
  for (int i = tid; i < BKT_NODES; i += 256) sc[0][i] = hist[i];
  __syncthreads();
  int pin = 0;
#pragma unroll
  for (int off = 1; off < BKT_NODES; off <<= 1) {
    for (int i = tid; i < BKT_NODES; i += 256) {
      int v = sc[pin][i];
      if (i >= off) v += sc[pin][i - off];
      sc[pin ^ 1][i] = v;
    }
    __syncthreads();
    pin ^= 1;
  }
  for (int i = tid; i < BKT_NODES; i += 256) {
    int excl = sc[pin][i] - hist[i];
    hist[i] = excl;  // reuse as cursor
    int g = node0 + i;
    if (g < N_NODES) rowptr[g] = base + excl;
  }
  __syncthreads();
  for (int i = tid; i < n; i += 256) {
    unsigned int rec = reg[i];
    int slot = atomicAdd(&hist[rec >> 17], 1);
    csr_src[base + slot] = (int)(rec & 0x1FFFFu);
  }
}

// ---------------------------------------------------------------------------
// Mean aggregation layer 1 (gather of bf16 x rows, f32 accumulate, f32 out).
// ---------------------------------------------------------------------------
__global__ __launch_bounds__(256) void agg_mean1_kernel(
    const unsigned short* __restrict__ xb, const int* __restrict__ rowptr,
    const int* __restrict__ csr, float* __restrict__ mean) {
  int t = blockIdx.x * blockDim.x + threadIdx.x;
  if (t >= N_NODES * (IN_C / 4)) return;
  int node = t >> 3;
  int q = t & 7;
  int p0 = rowptr[node], p1 = rowptr[node + 1];
  const ushort4* xb4 = (const ushort4*)xb;
  float ax = 0.f, ay = 0.f, az = 0.f, aw = 0.f;
  int k = p0;
  for (; k + 4 <= p1; k += 4) {
    int s0 = csr[k], s1 = csr[k + 1], s2 = csr[k + 2], s3 = csr[k + 3];
    ushort4 a = xb4[s0 * 8 + q];
    ushort4 b = xb4[s1 * 8 + q];
    ushort4 c = xb4[s2 * 8 + q];
    ushort4 d = xb4[s3 * 8 + q];
    ax += bf2f(a.x) + bf2f(b.x) + bf2f(c.x) + bf2f(d.x);
    ay += bf2f(a.y) + bf2f(b.y) + bf2f(c.y) + bf2f(d.y);
    az += bf2f(a.z) + bf2f(b.z) + bf2f(c.z) + bf2f(d.z);
    aw += bf2f(a.w) + bf2f(b.w) + bf2f(c.w) + bf2f(d.w);
  }
  for (; k < p1; ++k) {
    ushort4 a = xb4[csr[k] * 8 + q];
    ax += bf2f(a.x); ay += bf2f(a.y); az += bf2f(a.z); aw += bf2f(a.w);
  }
  float inv = 1.0f / fmaxf((float)(p1 - p0), 1.0f);
  float4 o; o.x = ax * inv; o.y = ay * inv; o.z = az * inv; o.w = aw * inv;
  ((float4*)mean)[t] = o;
}

// ---------------------------------------------------------------------------
// Mean aggregation layer 2: gather bf16 h1 rows, f32 accumulate,
// OUTPUT bf16 (meanb) — halves write stream, feeds bf16 layer2 staging.
// ---------------------------------------------------------------------------
__global__ __launch_bounds__(256) void agg_mean2_kernel(
    const unsigned short* __restrict__ hb, const int* __restrict__ rowptr,
    const int* __restrict__ csr, unsigned short* __restrict__ meanb) {
  int t = blockIdx.x * blockDim.x + threadIdx.x;
  if (t >= N_NODES * (HID_C / 4)) return;
  int node = t >> 4;
  int q = t & 15;
  int p0 = rowptr[node], p1 = rowptr[node + 1];
  const ushort4* hb4 = (const ushort4*)hb;
  float ax = 0.f, ay = 0.f, az = 0.f, aw = 0.f;
  int k = p0;
  for (; k + 4 <= p1; k += 4) {
    int s0 = csr[k], s1 = csr[k + 1], s2 = csr[k + 2], s3 = csr[k + 3];
    ushort4 a = hb4[s0 * 16 + q];
    ushort4 b = hb4[s1 * 16 + q];
    ushort4 c = hb4[s2 * 16 + q];
    ushort4 d = hb4[s3 * 16 + q];
    ax += bf2f(a.x) + bf2f(b.x) + bf2f(c.x) + bf2f(d.x);
    ay += bf2f(a.y) + bf2f(b.y) + bf2f(c.y) + bf2f(d.y);
    az += bf2f(a.z) + bf2f(b.z) + bf2f(c.z) + bf2f(d.z);
    aw += bf2f(a.w) + bf2f(b.w) + bf2f(c.w) + bf2f(d.w);
  }
  for (; k < p1; ++k) {
    ushort4 a = hb4[csr[k] * 16 + q];
    ax += bf2f(a.x); ay += bf2f(a.y); az += bf2f(a.z); aw += bf2f(a.w);
  }
  float inv = 1.0f / fmaxf((float)(p1 - p0), 1.0f);
  ushort4 ob;
  ob.x = f2bf(ax * inv); ob.y = f2bf(ay * inv);
  ob.z = f2bf(az * inv); ob.w = f2bf(aw * inv);
  ((ushort4*)meanb)[t] = ob;
}

// ---------------------------------------------------------------------------
// Layer 1 tiled GEMM (f32 staging; LDS ~35 KB = 4 blocks/CU already);
// epilogue writes h1 (f32) AND h1b (bf16).
// ---------------------------------------------------------------------------
__global__ __launch_bounds__(256) void layer1_gemm_kernel(
    const float* __restrict__ x, const float* __restrict__ mean,
    const float* __restrict__ Wl, const float* __restrict__ bl,
    const float* __restrict__ Wr, float* __restrict__ h1,
    unsigned short* __restrict__ h1b) {
  const int LD = 17;  // float4 row stride (16 data + 1 pad)
  __shared__ float4 sA[64 * LD];
  __shared__ float4 sB[64 * LD];
  __shared__ float sbias[64];
  int tid = threadIdx.x;
  int base = blockIdx.x * 64;
  const float4* mean4 = (const float4*)mean;
  const float4* x4 = (const float4*)x;
  const float4* Wl4 = (const float4*)Wl;
  const float4* Wr4 = (const float4*)Wr;
  const float4 zero = make_float4(0.f, 0.f, 0.f, 0.f);
  for (int idx = tid; idx < 64 * 16; idx += 256) {
    int row = idx >> 4, col = idx & 15;
    int node = base + row;
    float4 v = zero;
    if (node < N_NODES)
      v = (col < 8) ? mean4[node * 8 + col] : x4[node * 8 + (col - 8)];
    sA[row * LD + col] = v;
    sB[row * LD + col] = (col < 8) ? Wl4[row * 8 + col] : Wr4[row * 8 + (col - 8)];
  }
  if (tid < 64) sbias[tid] = bl[tid];
  __syncthreads();

  int tn = tid & 15;
  int to = tid >> 4;
  float acc[4][4];
#pragma unroll
  for (int i = 0; i < 4; ++i)
#pragma unroll
    for (int j = 0; j < 4; ++j) acc[i][j] = 0.f;

#pragma unroll 4
  for (int k4 = 0; k4 < 16; ++k4) {
    float4 a[4], b[4];
#pragma unroll
    for (int i = 0; i < 4; ++i) a[i] = sA[(tn + i * 16) * LD + k4];
#pragma unroll
    for (int j = 0; j < 4; ++j) b[j] = sB[(to * 4 + j) * LD + k4];
#pragma unroll
    for (int i = 0; i < 4; ++i)
#pragma unroll
      for (int j = 0; j < 4; ++j) {
        acc[i][j] = fmaf(a[i].x, b[j].x, acc[i][j]);
        acc[i][j] = fmaf(a[i].y, b[j].y, acc[i][j]);
        acc[i][j] = fmaf(a[i].z, b[j].z, acc[i][j]);
        acc[i][j] = fmaf(a[i].w, b[j].w, acc[i][j]);
      }
  }

  float4* h14 = (float4*)h1;
  ushort4* h1b4 = (ushort4*)h1b;
#pragma unroll
  for (int i = 0; i < 4; ++i) {
    int node = base + tn + i * 16;
    if (node < N_NODES) {
      float4 v;
      v.x = fmaxf(acc[i][0] + sbias[to * 4 + 0], 0.f);
      v.y = fmaxf(acc[i][1] + sbias[to * 4 + 1], 0.f);
      v.z = fmaxf(acc[i][2] + sbias[to * 4 + 2], 0.f);
      v.w = fmaxf(acc[i][3] + sbias[to * 4 + 3], 0.f);
      h14[node * 16 + to] = v;
      ushort4 hb;
      hb.x = f2bf(v.x); hb.y = f2bf(v.y); hb.z = f2bf(v.z); hb.w = f2bf(v.w);
      h1b4[node * 16 + to] = hb;
    }
  }
}

// ---------------------------------------------------------------------------
// Layer 2 + head fused, bf16 LDS staging (uint4 = 8 bf16 channels).
// LDS: 2*64*17*16 = 34816 B staging (reused as sH) + ~1.6 KB -> 4 blocks/CU.
// A = [mean2(bf16) | h1(bf16)], B = [W2l|W2r] converted to bf16 on stage.
// Accumulate f32.
// ---------------------------------------------------------------------------
__global__ __launch_bounds__(256) void layer2_head_kernel(
    const unsigned short* __restrict__ h1b, const unsigned short* __restrict__ meanb,
    const float* __restrict__ Wl, const float* __restrict__ bl,
    const float* __restrict__ Wr,
    const float* __restrict__ Wlin, const float* __restrict__ blin,
    float* __restrict__ out) {
  const int LDV = 17;  // uint4 row stride (16 data + 1 pad)
  __shared__ uint4 sbuf[2 * 64 * LDV];   // 34816 B; reused for sH (17664 B)
  __shared__ float sbias[64];
  __shared__ float sWlin[OUT_C * 64];
  __shared__ float sblin[OUT_C];
  uint4* sA = sbuf;
  uint4* sB = sbuf + 64 * LDV;
  int tid = threadIdx.x;
  int base = blockIdx.x * 64;
  const uint4* meanb4 = (const uint4*)meanb;  // 8 uint4 per node (64 bf16)
  const uint4* h1b4 = (const uint4*)h1b;      // 8 uint4 per node
  const float4* Wl4 = (const float4*)Wl;      // 16 float4 per row (64 f32)
  const float4* Wr4 = (const float4*)Wr;
  for (int idx = tid; idx < 64 * 16; idx += 256) {
    int row = idx >> 4, col = idx & 15;   // col = 8-channel group (0..15 of 128)
    int node = base + row;
    uint4 av = make_uint4(0u, 0u, 0u, 0u);
    if (node < N_NODES)
      av = (col < 8) ? meanb4[node * 8 + col] : h1b4[node * 8 + (col - 8)];
    sA[row * LDV + col] = av;
    float4 w0, w1;
    if (col < 8) {
      w0 = Wl4[row * 16 + 2 * col];
      w1 = Wl4[row * 16 + 2 * col + 1];
    } else {
      int c2 = col - 8;
      w0 = Wr4[row * 16 + 2 * c2];
      w1 = Wr4[row * 16 + 2 * c2 + 1];
    }
    uint4 bv;
    bv.x = (unsigned)f2bf(w0.x) | ((unsigned)f2bf(w0.y) << 16);
    bv.y = (unsigned)f2bf(w0.z) | ((unsigned)f2bf(w0.w) << 16);
    bv.z = (unsigned)f2bf(w1.x) | ((unsigned)f2bf(w1.y) << 16);
    bv.w = (unsigned)f2bf(w1.z) | ((unsigned)f2bf(w1.w) << 16);
    sB[row * LDV + col] = bv;
  }
  if (tid < 64) sbias[tid] = bl[tid];
  for (int i = tid; i < OUT_C * 64; i += 256) sWlin[i] = Wlin[i];
  if (tid < OUT_C) sblin[tid] = blin[tid];
  __syncthreads();

  int tn = tid & 15;
  int to = tid >> 4;
  float acc[4][4];
#pragma unroll
  for (int i = 0; i < 4; ++i)
#pragma unroll
    for (int j = 0; j < 4; ++j) acc[i][j] = 0.f;

#pragma unroll 2
  for (int k8 = 0; k8 < 16; ++k8) {
    float fa[4][8], fb[4][8];
#pragma unroll
    for (int i = 0; i < 4; ++i) {
      uint4 a = sA[(tn + i * 16) * LDV + k8];
      UNPK2(a.x, fa[i][0], fa[i][1]);
      UNPK2(a.y, fa[i][2], fa[i][3]);
      UNPK2(a.z, fa[i][4], fa[i][5]);
      UNPK2(a.w, fa[i][6], fa[i][7]);
    }
#pragma unroll
    for (int j = 0; j < 4; ++j) {
      uint4 b = sB[(to * 4 + j) * LDV + k8];
      UNPK2(b.x, fb[j][0], fb[j][1]);
      UNPK2(b.y, fb[j][2], fb[j][3]);
      UNPK2(b.z, fb[j][4], fb[j][5]);
      UNPK2(b.w, fb[j][6], fb[j][7]);
    }
#pragma unroll
    for (int i = 0; i < 4; ++i)
#pragma unroll
      for (int j = 0; j < 4; ++j) {
#pragma unroll
        for (int c = 0; c < 8; ++c)
          acc[i][j] = fmaf(fa[i][c], fb[j][c], acc[i][j]);
      }
  }

  __syncthreads();  // staging done -> reuse sbuf as sH
  float* sH = (float*)sbuf;
  const int LDH = 69;  // gcd(69 mod 32, 32) = 1 -> conflict-free column walks
#pragma unroll
  for (int i = 0; i < 4; ++i) {
    int r = tn + i * 16;
#pragma unroll
    for (int j = 0; j < 4; ++j) {
      sH[r * LDH + to * 4 + j] = fmaxf(acc[i][j] + sbias[to * 4 + j], 0.f);
    }
  }
  __syncthreads();

  if (tid < 64) {
    int node = base + tid;
    if (node < N_NODES) {
      float o5[OUT_C];
#pragma unroll
      for (int m = 0; m < OUT_C; ++m) o5[m] = sblin[m];
      const float* hr = &sH[tid * LDH];
#pragma unroll 8
      for (int c = 0; c < HID_C; ++c) {
        float v = hr[c];
#pragma unroll
        for (int m = 0; m < OUT_C; ++m) o5[m] = fmaf(v, sWlin[m * 64 + c], o5[m]);
      }
#pragma unroll
      for (int m = 0; m < OUT_C; ++m) out[node * OUT_C + m] = o5[m];
    }
  }
}

extern "C" void kernel_launch(void* const* d_in, const int* in_sizes, int n_in,
                              void* d_out, int out_size, void* d_ws, size_t ws_size,
                              hipStream_t stream) {
  const float* x    = (const float*)d_in[0];
  const int*   ei   = (const int*)d_in[1];
  const float* W1l  = (const float*)d_in[2];
  const float* b1   = (const float*)d_in[3];
  const float* W1r  = (const float*)d_in[4];
  const float* W2l  = (const float*)d_in[5];
  const float* b2   = (const float*)d_in[6];
  const float* W2r  = (const float*)d_in[7];
  const float* Wlin = (const float*)d_in[8];
  const float* blin = (const float*)d_in[9];

  const int* src = ei;
  const int* dst = ei + N_EDGES;

  // Workspace layout (4B units):
  //   rowptr      [100004]
  //   bucket_cur  [256]
  //   bucket_base [256]
  //   region      [196*10240 u32 = 8.0 MB]
  //   csr_src     [1600000]
  //   xb          [N*32 bf16 = 6.4 MB]
  //   h1b         [N*64 bf16 = 12.8 MB]
  //   meanb       [N*64 bf16 = 12.8 MB]
  //   mean        [N*64 f32  = 25.6 MB]  (layer-1 path)
  //   h1          [N*64 f32  = 25.6 MB]
  int* rowptr       = (int*)d_ws;
  int* bucket_cur   = rowptr + 100004;
  int* bucket_base  = bucket_cur + 256;
  unsigned int* region = (unsigned int*)(bucket_base + 256);
  int* csr_src      = (int*)(region + (size_t)NBKT * BKT_CAP);
  unsigned short* xb    = (unsigned short*)(csr_src + N_EDGES);
  unsigned short* h1b   = xb + (size_t)N_NODES * IN_C;
  unsigned short* meanb = h1b + (size_t)N_NODES * HID_C;
  float* mean = (float*)(meanb + (size_t)N_NODES * HID_C);
  float* h1   = mean + (size_t)N_NODES * HID_C;

  hipMemsetAsync(bucket_cur, 0, 256 * sizeof(int), stream);

  convert_x_kernel<<<(N_NODES * IN_C / 4 + 255) / 256, 256, 0, stream>>>(x, xb);
  p1_bin_kernel<<<NP1, 256, 0, stream>>>(src, dst, region, bucket_cur);
  bucket_scan_kernel<<<1, 256, 0, stream>>>(bucket_cur, bucket_base, rowptr);
  p2_csr_kernel<<<NBKT, 256, 0, stream>>>(region, bucket_cur, bucket_base,
                                          rowptr, csr_src);

  agg_mean1_kernel<<<(N_NODES * (IN_C / 4) + 255) / 256, 256, 0, stream>>>(
      xb, rowptr, csr_src, mean);
  layer1_gemm_kernel<<<N_TILES, 256, 0, stream>>>(
      x, mean, W1l, b1, W1r, h1, h1b);
  agg_mean2_kernel<<<(N_NODES * (HID_C / 4) + 255) / 256, 256, 0, stream>>>(
      h1b, rowptr, csr_src, meanb);
  layer2_head_kernel<<<N_TILES, 256, 0, stream>>>(
      h1b, meanb, W2l, b2, W2r, Wlin, blin, (float*)d_out);
}

// Round 22
// 198.334 us; speedup vs baseline: 1.3485x; 1.0155x over previous
//
#include <hip/hip_runtime.h>

#define N_NODES 100000
#define IN_C 32
#define HID_C 64
#define OUT_C 5
#define N_EDGES 1600000
#define N_TILES ((N_NODES + 63) / 64)   // 1563

// Bucketed CSR build: 196 buckets of 512 nodes; per-edge atomics in LDS only.
#define BKT_SHIFT 9
#define BKT_NODES 512
#define NBKT 196                         // ceil(100000/512)
#define BKT_CAP 10240                    // mean 8163, +23 sigma
#define P1_CHUNK 4096
#define NP1 ((N_EDGES + P1_CHUNK - 1) / P1_CHUNK)   // 391

__device__ __forceinline__ unsigned short f2bf(float f) {
  unsigned int u = __float_as_uint(f);
  unsigned int r = (u + 0x7FFFu + ((u >> 16) & 1u)) >> 16;  // RNE
  return (unsigned short)r;
}
__device__ __forceinline__ float bf2f(unsigned short b) {
  return __uint_as_float(((unsigned int)b) << 16);
}
// unpack a uint32 holding two bf16 (lo | hi<<16) into two floats
#define UNPK2(u, f0, f1)                         \
  {                                              \
    f0 = __uint_as_float((u) << 16);             \
    f1 = __uint_as_float((u) & 0xFFFF0000u);     \
  }

// ---------------------------------------------------------------------------
// Convert x (f32 [N,32]) -> xb (bf16).
// ---------------------------------------------------------------------------
__global__ __launch_bounds__(256) void convert_x_kernel(
    const float* __restrict__ x, unsigned short* __restrict__ xb) {
  int t = blockIdx.x * blockDim.x + threadIdx.x;
  if (t >= N_NODES * IN_C / 4) return;
  float4 v = ((const float4*)x)[t];
  ushort4 o;
  o.x = f2bf(v.x); o.y = f2bf(v.y); o.z = f2bf(v.z); o.w = f2bf(v.w);
  ((ushort4*)xb)[t] = o;
}

// ---------------------------------------------------------------------------
// Pass 1: bin edges into 196 dst-buckets (LDS-only per-edge atomics).
// ---------------------------------------------------------------------------
__global__ __launch_bounds__(256) void p1_bin_kernel(
    const int* __restrict__ src, const int* __restrict__ dst,
    unsigned int* __restrict__ region, int* __restrict__ bucket_cur) {
  __shared__ int lhist[NBKT];
  __shared__ int gbase[NBKT];
  int tid = threadIdx.x;
  for (int i = tid; i < NBKT; i += 256) lhist[i] = 0;
  __syncthreads();
  int e0 = blockIdx.x * P1_CHUNK;
  for (int i = tid; i < P1_CHUNK; i += 256) {
    int e = e0 + i;
    if (e < N_EDGES) atomicAdd(&lhist[dst[e] >> BKT_SHIFT], 1);
  }
  __syncthreads();
  for (int i = tid; i < NBKT; i += 256) {
    int c = lhist[i];
    gbase[i] = (c > 0) ? atomicAdd(&bucket_cur[i], c) : 0;
    lhist[i] = 0;  // reuse as local cursor
  }
  __syncthreads();
  for (int i = tid; i < P1_CHUNK; i += 256) {
    int e = e0 + i;
    if (e < N_EDGES) {
      int d = dst[e];
      int b = d >> BKT_SHIFT;
      unsigned int rec =
          ((unsigned int)(d & (BKT_NODES - 1)) << 17) | (unsigned int)src[e];
      int slot = atomicAdd(&lhist[b], 1);
      int pos = gbase[b] + slot;
      if (pos < BKT_CAP) region[(size_t)b * BKT_CAP + pos] = rec;
    }
  }
}

// ---------------------------------------------------------------------------
// Scan of 196 bucket counts -> bucket_base; rowptr[N] = total.
// ---------------------------------------------------------------------------
__global__ __launch_bounds__(256) void bucket_scan_kernel(
    const int* __restrict__ bucket_cur, int* __restrict__ bucket_base,
    int* __restrict__ rowptr) {
  __shared__ int s[2][256];
  int t = threadIdx.x;
  int v = 0;
  if (t < NBKT) { v = bucket_cur[t]; if (v > BKT_CAP) v = BKT_CAP; }
  s[0][t] = v;
  __syncthreads();
  int pin = 0;
#pragma unroll
  for (int off = 1; off < 256; off <<= 1) {
    int u = s[pin][t];
    if (t >= off) u += s[pin][t - off];
    s[pin ^ 1][t] = u;
    __syncthreads();
    pin ^= 1;
  }
  if (t < NBKT) bucket_base[t] = s[pin][t] - v;  // exclusive
  if (t == 0) rowptr[N_NODES] = s[pin][NBKT - 1];
}

// ---------------------------------------------------------------------------
// Pass 2: per-bucket LDS histogram + scan + placement; coalesced writes.
// ---------------------------------------------------------------------------
__global__ __launch_bounds__(256) void p2_csr_kernel(
    const unsigned int* __restrict__ region, const int* __restrict__ bucket_cur,
    const int* __restrict__ bucket_base, int* __restrict__ rowptr,
    int* __restrict__ csr_src) {
  __shared__ int hist[BKT_NODES];
  __shared__ int sc[2][BKT_NODES];
  int tid = threadIdx.x;
  int b = blockIdx.x;
  int n = bucket_cur[b]; if (n > BKT_CAP) n = BKT_CAP;
  int base = bucket_base[b];
  int node0 = b << BKT_SHIFT;
  const unsigned int* reg = region + (size_t)b * BKT_CAP;

  for (int i = tid; i < BKT_NODES; i += 256) hist[i] = 0;
  __syncthreads();
  for (int i = tid; i < n; i += 256) atomicAdd(&hist[reg[i] >> 17], 1);
  __syncthreads();
  for (int i = tid; i < BKT_NODES; i += 256) sc[0][i] = hist[i];
  __syncthreads();
  int pin = 0;
#pragma unroll
  for (int off = 1; off < BKT_NODES; off <<= 1) {
    for (int i = tid; i < BKT_NODES; i += 256) {
      int v = sc[pin][i];
      if (i >= off) v += sc[pin][i - off];
      sc[pin ^ 1][i] = v;
    }
    __syncthreads();
    pin ^= 1;
  }
  for (int i = tid; i < BKT_NODES; i += 256) {
    int excl = sc[pin][i] - hist[i];
    hist[i] = excl;  // reuse as cursor
    int g = node0 + i;
    if (g < N_NODES) rowptr[g] = base + excl;
  }
  __syncthreads();
  for (int i = tid; i < n; i += 256) {
    unsigned int rec = reg[i];
    int slot = atomicAdd(&hist[rec >> 17], 1);
    csr_src[base + slot] = (int)(rec & 0x1FFFFu);
  }
}

// ---------------------------------------------------------------------------
// Mean aggregation layer 1: gather bf16 x rows, f32 accumulate, bf16 OUT.
// ---------------------------------------------------------------------------
__global__ __launch_bounds__(256) void agg_mean1_kernel(
    const unsigned short* __restrict__ xb, const int* __restrict__ rowptr,
    const int* __restrict__ csr, unsigned short* __restrict__ meanb1) {
  int t = blockIdx.x * blockDim.x + threadIdx.x;
  if (t >= N_NODES * (IN_C / 4)) return;
  int node = t >> 3;
  int q = t & 7;
  int p0 = rowptr[node], p1 = rowptr[node + 1];
  const ushort4* xb4 = (const ushort4*)xb;
  float ax = 0.f, ay = 0.f, az = 0.f, aw = 0.f;
  int k = p0;
  for (; k + 4 <= p1; k += 4) {
    int s0 = csr[k], s1 = csr[k + 1], s2 = csr[k + 2], s3 = csr[k + 3];
    ushort4 a = xb4[s0 * 8 + q];
    ushort4 b = xb4[s1 * 8 + q];
    ushort4 c = xb4[s2 * 8 + q];
    ushort4 d = xb4[s3 * 8 + q];
    ax += bf2f(a.x) + bf2f(b.x) + bf2f(c.x) + bf2f(d.x);
    ay += bf2f(a.y) + bf2f(b.y) + bf2f(c.y) + bf2f(d.y);
    az += bf2f(a.z) + bf2f(b.z) + bf2f(c.z) + bf2f(d.z);
    aw += bf2f(a.w) + bf2f(b.w) + bf2f(c.w) + bf2f(d.w);
  }
  for (; k < p1; ++k) {
    ushort4 a = xb4[csr[k] * 8 + q];
    ax += bf2f(a.x); ay += bf2f(a.y); az += bf2f(a.z); aw += bf2f(a.w);
  }
  float inv = 1.0f / fmaxf((float)(p1 - p0), 1.0f);
  ushort4 ob;
  ob.x = f2bf(ax * inv); ob.y = f2bf(ay * inv);
  ob.z = f2bf(az * inv); ob.w = f2bf(aw * inv);
  ((ushort4*)meanb1)[t] = ob;
}

// ---------------------------------------------------------------------------
// Mean aggregation layer 2: gather bf16 h1 rows, f32 accumulate, bf16 OUT.
// ---------------------------------------------------------------------------
__global__ __launch_bounds__(256) void agg_mean2_kernel(
    const unsigned short* __restrict__ hb, const int* __restrict__ rowptr,
    const int* __restrict__ csr, unsigned short* __restrict__ meanb) {
  int t = blockIdx.x * blockDim.x + threadIdx.x;
  if (t >= N_NODES * (HID_C / 4)) return;
  int node = t >> 4;
  int q = t & 15;
  int p0 = rowptr[node], p1 = rowptr[node + 1];
  const ushort4* hb4 = (const ushort4*)hb;
  float ax = 0.f, ay = 0.f, az = 0.f, aw = 0.f;
  int k = p0;
  for (; k + 4 <= p1; k += 4) {
    int s0 = csr[k], s1 = csr[k + 1], s2 = csr[k + 2], s3 = csr[k + 3];
    ushort4 a = hb4[s0 * 16 + q];
    ushort4 b = hb4[s1 * 16 + q];
    ushort4 c = hb4[s2 * 16 + q];
    ushort4 d = hb4[s3 * 16 + q];
    ax += bf2f(a.x) + bf2f(b.x) + bf2f(c.x) + bf2f(d.x);
    ay += bf2f(a.y) + bf2f(b.y) + bf2f(c.y) + bf2f(d.y);
    az += bf2f(a.z) + bf2f(b.z) + bf2f(c.z) + bf2f(d.z);
    aw += bf2f(a.w) + bf2f(b.w) + bf2f(c.w) + bf2f(d.w);
  }
  for (; k < p1; ++k) {
    ushort4 a = hb4[csr[k] * 16 + q];
    ax += bf2f(a.x); ay += bf2f(a.y); az += bf2f(a.z); aw += bf2f(a.w);
  }
  float inv = 1.0f / fmaxf((float)(p1 - p0), 1.0f);
  ushort4 ob;
  ob.x = f2bf(ax * inv); ob.y = f2bf(ay * inv);
  ob.z = f2bf(az * inv); ob.w = f2bf(aw * inv);
  ((ushort4*)meanb)[t] = ob;
}

// ---------------------------------------------------------------------------
// Layer 1 GEMM, bf16 staging (K=64): h1b = relu([mean1|x]@[W1l;W1r]^T + b1).
// LDS ~18.7 KB. Writes ONLY h1b (f32 h1 was dead — layer2 reads bf16).
// ---------------------------------------------------------------------------
__global__ __launch_bounds__(256) void layer1_gemm_kernel(
    const unsigned short* __restrict__ xb, const unsigned short* __restrict__ meanb1,
    const float* __restrict__ Wl, const float* __restrict__ bl,
    const float* __restrict__ Wr, unsigned short* __restrict__ h1b) {
  const int LDV = 9;  // uint4 row stride (8 data + 1 pad)
  __shared__ uint4 sA[64 * LDV];
  __shared__ uint4 sB[64 * LDV];
  __shared__ float sbias[64];
  int tid = threadIdx.x;
  int base = blockIdx.x * 64;
  const uint4* meanb14 = (const uint4*)meanb1;  // 4 uint4 per node (32 bf16)
  const uint4* xb4 = (const uint4*)xb;          // 4 uint4 per node
  const float4* Wl4 = (const float4*)Wl;        // 8 float4 per row (32 f32)
  const float4* Wr4 = (const float4*)Wr;
  for (int idx = tid; idx < 64 * 8; idx += 256) {
    int row = idx >> 3, col = idx & 7;  // col = 8-channel group (0..7 of 64)
    int node = base + row;
    uint4 av = make_uint4(0u, 0u, 0u, 0u);
    if (node < N_NODES)
      av = (col < 4) ? meanb14[node * 4 + col] : xb4[node * 4 + (col - 4)];
    sA[row * LDV + col] = av;
    float4 w0, w1;
    if (col < 4) {
      w0 = Wl4[row * 8 + 2 * col];
      w1 = Wl4[row * 8 + 2 * col + 1];
    } else {
      int c2 = col - 4;
      w0 = Wr4[row * 8 + 2 * c2];
      w1 = Wr4[row * 8 + 2 * c2 + 1];
    }
    uint4 bv;
    bv.x = (unsigned)f2bf(w0.x) | ((unsigned)f2bf(w0.y) << 16);
    bv.y = (unsigned)f2bf(w0.z) | ((unsigned)f2bf(w0.w) << 16);
    bv.z = (unsigned)f2bf(w1.x) | ((unsigned)f2bf(w1.y) << 16);
    bv.w = (unsigned)f2bf(w1.z) | ((unsigned)f2bf(w1.w) << 16);
    sB[row * LDV + col] = bv;
  }
  if (tid < 64) sbias[tid] = bl[tid];
  __syncthreads();

  int tn = tid & 15;
  int to = tid >> 4;
  float acc[4][4];
#pragma unroll
  for (int i = 0; i < 4; ++i)
#pragma unroll
    for (int j = 0; j < 4; ++j) acc[i][j] = 0.f;

#pragma unroll 2
  for (int k8 = 0; k8 < 8; ++k8) {
    float fa[4][8], fb[4][8];
#pragma unroll
    for (int i = 0; i < 4; ++i) {
      uint4 a = sA[(tn + i * 16) * LDV + k8];
      UNPK2(a.x, fa[i][0], fa[i][1]);
      UNPK2(a.y, fa[i][2], fa[i][3]);
      UNPK2(a.z, fa[i][4], fa[i][5]);
      UNPK2(a.w, fa[i][6], fa[i][7]);
    }
#pragma unroll
    for (int j = 0; j < 4; ++j) {
      uint4 b = sB[(to * 4 + j) * LDV + k8];
      UNPK2(b.x, fb[j][0], fb[j][1]);
      UNPK2(b.y, fb[j][2], fb[j][3]);
      UNPK2(b.z, fb[j][4], fb[j][5]);
      UNPK2(b.w, fb[j][6], fb[j][7]);
    }
#pragma unroll
    for (int i = 0; i < 4; ++i)
#pragma unroll
      for (int j = 0; j < 4; ++j) {
#pragma unroll
        for (int c = 0; c < 8; ++c)
          acc[i][j] = fmaf(fa[i][c], fb[j][c], acc[i][j]);
      }
  }

  ushort4* h1b4 = (ushort4*)h1b;
#pragma unroll
  for (int i = 0; i < 4; ++i) {
    int node = base + tn + i * 16;
    if (node < N_NODES) {
      ushort4 hb;
      hb.x = f2bf(fmaxf(acc[i][0] + sbias[to * 4 + 0], 0.f));
      hb.y = f2bf(fmaxf(acc[i][1] + sbias[to * 4 + 1], 0.f));
      hb.z = f2bf(fmaxf(acc[i][2] + sbias[to * 4 + 2], 0.f));
      hb.w = f2bf(fmaxf(acc[i][3] + sbias[to * 4 + 3], 0.f));
      h1b4[node * 16 + to] = hb;
    }
  }
}

// ---------------------------------------------------------------------------
// Layer 2 + head fused, bf16 LDS staging (uint4 = 8 bf16 channels).
// ---------------------------------------------------------------------------
__global__ __launch_bounds__(256) void layer2_head_kernel(
    const unsigned short* __restrict__ h1b, const unsigned short* __restrict__ meanb,
    const float* __restrict__ Wl, const float* __restrict__ bl,
    const float* __restrict__ Wr,
    const float* __restrict__ Wlin, const float* __restrict__ blin,
    float* __restrict__ out) {
  const int LDV = 17;  // uint4 row stride (16 data + 1 pad)
  __shared__ uint4 sbuf[2 * 64 * LDV];   // 34816 B; reused for sH (17664 B)
  __shared__ float sbias[64];
  __shared__ float sWlin[OUT_C * 64];
  __shared__ float sblin[OUT_C];
  uint4* sA = sbuf;
  uint4* sB = sbuf + 64 * LDV;
  int tid = threadIdx.x;
  int base = blockIdx.x * 64;
  const uint4* meanb4 = (const uint4*)meanb;  // 8 uint4 per node (64 bf16)
  const uint4* h1b4 = (const uint4*)h1b;      // 8 uint4 per node
  const float4* Wl4 = (const float4*)Wl;      // 16 float4 per row (64 f32)
  const float4* Wr4 = (const float4*)Wr;
  for (int idx = tid; idx < 64 * 16; idx += 256) {
    int row = idx >> 4, col = idx & 15;   // col = 8-channel group (0..15 of 128)
    int node = base + row;
    uint4 av = make_uint4(0u, 0u, 0u, 0u);
    if (node < N_NODES)
      av = (col < 8) ? meanb4[node * 8 + col] : h1b4[node * 8 + (col - 8)];
    sA[row * LDV + col] = av;
    float4 w0, w1;
    if (col < 8) {
      w0 = Wl4[row * 16 + 2 * col];
      w1 = Wl4[row * 16 + 2 * col + 1];
    } else {
      int c2 = col - 8;
      w0 = Wr4[row * 16 + 2 * c2];
      w1 = Wr4[row * 16 + 2 * c2 + 1];
    }
    uint4 bv;
    bv.x = (unsigned)f2bf(w0.x) | ((unsigned)f2bf(w0.y) << 16);
    bv.y = (unsigned)f2bf(w0.z) | ((unsigned)f2bf(w0.w) << 16);
    bv.z = (unsigned)f2bf(w1.x) | ((unsigned)f2bf(w1.y) << 16);
    bv.w = (unsigned)f2bf(w1.z) | ((unsigned)f2bf(w1.w) << 16);
    sB[row * LDV + col] = bv;
  }
  if (tid < 64) sbias[tid] = bl[tid];
  for (int i = tid; i < OUT_C * 64; i += 256) sWlin[i] = Wlin[i];
  if (tid < OUT_C) sblin[tid] = blin[tid];
  __syncthreads();

  int tn = tid & 15;
  int to = tid >> 4;
  float acc[4][4];
#pragma unroll
  for (int i = 0; i < 4; ++i)
#pragma unroll
    for (int j = 0; j < 4; ++j) acc[i][j] = 0.f;

#pragma unroll 2
  for (int k8 = 0; k8 < 16; ++k8) {
    float fa[4][8], fb[4][8];
#pragma unroll
    for (int i = 0; i < 4; ++i) {
      uint4 a = sA[(tn + i * 16) * LDV + k8];
      UNPK2(a.x, fa[i][0], fa[i][1]);
      UNPK2(a.y, fa[i][2], fa[i][3]);
      UNPK2(a.z, fa[i][4], fa[i][5]);
      UNPK2(a.w, fa[i][6], fa[i][7]);
    }
#pragma unroll
    for (int j = 0; j < 4; ++j) {
      uint4 b = sB[(to * 4 + j) * LDV + k8];
      UNPK2(b.x, fb[j][0], fb[j][1]);
      UNPK2(b.y, fb[j][2], fb[j][3]);
      UNPK2(b.z, fb[j][4], fb[j][5]);
      UNPK2(b.w, fb[j][6], fb[j][7]);
    }
#pragma unroll
    for (int i = 0; i < 4; ++i)
#pragma unroll
      for (int j = 0; j < 4; ++j) {
#pragma unroll
        for (int c = 0; c < 8; ++c)
          acc[i][j] = fmaf(fa[i][c], fb[j][c], acc[i][j]);
      }
  }

  __syncthreads();  // staging done -> reuse sbuf as sH
  float* sH = (float*)sbuf;
  const int LDH = 69;  // gcd(69 mod 32, 32) = 1 -> conflict-free column walks
#pragma unroll
  for (int i = 0; i < 4; ++i) {
    int r = tn + i * 16;
#pragma unroll
    for (int j = 0; j < 4; ++j) {
      sH[r * LDH + to * 4 + j] = fmaxf(acc[i][j] + sbias[to * 4 + j], 0.f);
    }
  }
  __syncthreads();

  if (tid < 64) {
    int node = base + tid;
    if (node < N_NODES) {
      float o5[OUT_C];
#pragma unroll
      for (int m = 0; m < OUT_C; ++m) o5[m] = sblin[m];
      const float* hr = &sH[tid * LDH];
#pragma unroll 8
      for (int c = 0; c < HID_C; ++c) {
        float v = hr[c];
#pragma unroll
        for (int m = 0; m < OUT_C; ++m) o5[m] = fmaf(v, sWlin[m * 64 + c], o5[m]);
      }
#pragma unroll
      for (int m = 0; m < OUT_C; ++m) out[node * OUT_C + m] = o5[m];
    }
  }
}

extern "C" void kernel_launch(void* const* d_in, const int* in_sizes, int n_in,
                              void* d_out, int out_size, void* d_ws, size_t ws_size,
                              hipStream_t stream) {
  const float* x    = (const float*)d_in[0];
  const int*   ei   = (const int*)d_in[1];
  const float* W1l  = (const float*)d_in[2];
  const float* b1   = (const float*)d_in[3];
  const float* W1r  = (const float*)d_in[4];
  const float* W2l  = (const float*)d_in[5];
  const float* b2   = (const float*)d_in[6];
  const float* W2r  = (const float*)d_in[7];
  const float* Wlin = (const float*)d_in[8];
  const float* blin = (const float*)d_in[9];

  const int* src = ei;
  const int* dst = ei + N_EDGES;

  // Workspace layout (4B units):
  //   rowptr      [100004]
  //   bucket_cur  [256]
  //   bucket_base [256]
  //   region      [196*10240 u32 = 8.0 MB]
  //   csr_src     [1600000]
  //   xb          [N*32 bf16 = 6.4 MB]
  //   h1b         [N*64 bf16 = 12.8 MB]
  //   meanb       [N*64 bf16 = 12.8 MB]
  //   meanb1      [N*32 bf16 = 6.4 MB]
  int* rowptr       = (int*)d_ws;
  int* bucket_cur   = rowptr + 100004;
  int* bucket_base  = bucket_cur + 256;
  unsigned int* region = (unsigned int*)(bucket_base + 256);
  int* csr_src      = (int*)(region + (size_t)NBKT * BKT_CAP);
  unsigned short* xb     = (unsigned short*)(csr_src + N_EDGES);
  unsigned short* h1b    = xb + (size_t)N_NODES * IN_C;
  unsigned short* meanb  = h1b + (size_t)N_NODES * HID_C;
  unsigned short* meanb1 = meanb + (size_t)N_NODES * HID_C;

  hipMemsetAsync(bucket_cur, 0, 256 * sizeof(int), stream);

  convert_x_kernel<<<(N_NODES * IN_C / 4 + 255) / 256, 256, 0, stream>>>(x, xb);
  p1_bin_kernel<<<NP1, 256, 0, stream>>>(src, dst, region, bucket_cur);
  bucket_scan_kernel<<<1, 256, 0, stream>>>(bucket_cur, bucket_base, rowptr);
  p2_csr_kernel<<<NBKT, 256, 0, stream>>>(region, bucket_cur, bucket_base,
                                          rowptr, csr_src);

  agg_mean1_kernel<<<(N_NODES * (IN_C / 4) + 255) / 256, 256, 0, stream>>>(
      xb, rowptr, csr_src, meanb1);
  layer1_gemm_kernel<<<N_TILES, 256, 0, stream>>>(
      xb, meanb1, W1l, b1, W1r, h1b);
  agg_mean2_kernel<<<(N_NODES * (HID_C / 4) + 255) / 256, 256, 0, stream>>>(
      h1b, rowptr, csr_src, meanb);
  layer2_head_kernel<<<N_TILES, 256, 0, stream>>>(
      h1b, meanb, W2l, b2, W2r, Wlin, blin, (float*)d_out);
}